// Round 1
// baseline (10162.662 us; speedup 1.0000x reference)
//
#include <hip/hip_runtime.h>

#define N_USERS 100000
#define N_ITEMS 50000
#define N_NODES 150000
#define DIM 64
#define NNZ 4000000
#define BATCH 4096

// ---------------- init: concat user/item embeddings into X and ACC ----------
__global__ void init_k(const float4* __restrict__ ue, const float4* __restrict__ ie,
                       float4* __restrict__ X, float4* __restrict__ ACC) {
    int i = blockIdx.x * blockDim.x + threadIdx.x;
    const int total  = N_NODES * DIM / 4;   // 2.4M float4
    const int ubound = N_USERS * DIM / 4;   // 1.6M float4
    if (i < total) {
        float4 v = (i < ubound) ? ue[i] : ie[i - ubound];
        X[i]   = v;
        ACC[i] = v;
    }
}

// ---------------- scatter: Y[dst] += val * X[src], 16 threads per edge ------
__global__ void scatter_k(const int* __restrict__ src, const int* __restrict__ dst,
                          const float* __restrict__ val,
                          const float4* __restrict__ X, float* __restrict__ Y) {
    int t = blockIdx.x * blockDim.x + threadIdx.x;   // NNZ*16 = 64M < 2^31
    if (t >= NNZ * 16) return;
    int e = t >> 4;
    int q = t & 15;
    int s = src[e];
    int d = dst[e];
    float v = val[e];
    float4 x = X[s * 16 + q];
    float* yp = Y + (d * 64 + q * 4);
    atomicAdd(yp + 0, v * x.x);
    atomicAdd(yp + 1, v * x.y);
    atomicAdd(yp + 2, v * x.z);
    atomicAdd(yp + 3, v * x.w);
}

// ---------------- ACC += Y ---------------------------------------------------
__global__ void accadd_k(float4* __restrict__ ACC, const float4* __restrict__ Y) {
    int i = blockIdx.x * blockDim.x + threadIdx.x;
    const int total = N_NODES * DIM / 4;
    if (i < total) {
        float4 a = ACC[i];
        float4 y = Y[i];
        a.x += y.x; a.y += y.y; a.z += y.z; a.w += y.w;
        ACC[i] = a;
    }
}

// ---------------- final: gather rows, dot, sigmoid ---------------------------
__global__ void final_k(const int* __restrict__ users, const int* __restrict__ items,
                        const float* __restrict__ ACC, float* __restrict__ out) {
    int b    = blockIdx.x * (blockDim.x / 64) + (threadIdx.x / 64);
    int lane = threadIdx.x & 63;
    if (b >= BATCH) return;
    int ur = users[b];
    int ir = N_USERS + items[b];
    float u  = ACC[ur * 64 + lane];
    float it = ACC[ir * 64 + lane];
    float p  = u * it * (1.0f / 16.0f);   // light_out = acc/4 on both sides
    #pragma unroll
    for (int off = 32; off; off >>= 1) p += __shfl_down(p, off, 64);
    if (lane == 0) out[b] = 1.0f / (1.0f + __expf(-p));
}

extern "C" void kernel_launch(void* const* d_in, const int* in_sizes, int n_in,
                              void* d_out, int out_size, void* d_ws, size_t ws_size,
                              hipStream_t stream) {
    const int*   users = (const int*)  d_in[0];
    const int*   items = (const int*)  d_in[1];
    const int*   esrc  = (const int*)  d_in[2];
    const int*   edst  = (const int*)  d_in[3];
    const float* eval  = (const float*)d_in[4];
    const float* uemb  = (const float*)d_in[5];
    const float* iemb  = (const float*)d_in[6];
    float*       out   = (float*)      d_out;

    const size_t SZ = (size_t)N_NODES * DIM * sizeof(float);   // 38.4 MB
    char* ws = (char*)d_ws;
    float* X   = (float*)(ws);
    float* Y   = (float*)(ws + SZ);
    float* ACC = (float*)(ws + 2 * SZ);

    const int totv = N_NODES * DIM / 4;
    init_k<<<(totv + 255) / 256, 256, 0, stream>>>(
        (const float4*)uemb, (const float4*)iemb, (float4*)X, (float4*)ACC);

    for (int l = 0; l < 3; ++l) {
        hipMemsetAsync(Y, 0, SZ, stream);
        const int nt = NNZ * 16;
        scatter_k<<<(nt + 255) / 256, 256, 0, stream>>>(esrc, edst, eval,
                                                        (const float4*)X, Y);
        accadd_k<<<(totv + 255) / 256, 256, 0, stream>>>((float4*)ACC, (const float4*)Y);
        float* tmp = X; X = Y; Y = tmp;
    }

    final_k<<<(BATCH * 64 + 255) / 256, 256, 0, stream>>>(users, items, ACC, out);
}

// Round 2
// 1117.622 us; speedup vs baseline: 9.0931x; 9.0931x over previous
//
#include <hip/hip_runtime.h>

#define N_USERS 100000
#define N_ITEMS 50000
#define N_NODES 150000
#define DIM 64
#define NNZ 4000000
#define BATCH 4096

// ---------------- init: concat user/item embeddings into X and ACC ----------
__global__ void init_k(const float4* __restrict__ ue, const float4* __restrict__ ie,
                       float4* __restrict__ X, float4* __restrict__ ACC) {
    int i = blockIdx.x * blockDim.x + threadIdx.x;
    const int total  = N_NODES * DIM / 4;   // 2.4M float4
    const int ubound = N_USERS * DIM / 4;   // 1.6M float4
    if (i < total) {
        float4 v = (i < ubound) ? ue[i] : ie[i - ubound];
        X[i]   = v;
        ACC[i] = v;
    }
}

// ---------------- CSR build --------------------------------------------------
__global__ void hist_k(const int* __restrict__ dst, int* __restrict__ cnt) {
    int e = blockIdx.x * blockDim.x + threadIdx.x;
    if (e < NNZ) atomicAdd(&cnt[dst[e]], 1);
}

// block scans 1024 counts (256 thr x 4), writes local-exclusive + block sum
__global__ void scan1_k(const int* __restrict__ cnt, int* __restrict__ row,
                        int* __restrict__ bsum) {
    __shared__ int sh[256];
    int tid  = threadIdx.x;
    int base = blockIdx.x * 1024 + tid * 4;
    int v0 = (base + 0 < N_NODES) ? cnt[base + 0] : 0;
    int v1 = (base + 1 < N_NODES) ? cnt[base + 1] : 0;
    int v2 = (base + 2 < N_NODES) ? cnt[base + 2] : 0;
    int v3 = (base + 3 < N_NODES) ? cnt[base + 3] : 0;
    int tsum = v0 + v1 + v2 + v3;
    sh[tid] = tsum;
    __syncthreads();
    for (int off = 1; off < 256; off <<= 1) {
        int t = (tid >= off) ? sh[tid - off] : 0;
        __syncthreads();
        sh[tid] += t;
        __syncthreads();
    }
    if (tid == 255) bsum[blockIdx.x] = sh[255];
    int excl = sh[tid] - tsum;
    if (base + 0 < N_NODES) row[base + 0] = excl;           excl += v0;
    if (base + 1 < N_NODES) row[base + 1] = excl;           excl += v1;
    if (base + 2 < N_NODES) row[base + 2] = excl;           excl += v2;
    if (base + 3 < N_NODES) row[base + 3] = excl;
}

// single-block exclusive scan of block sums (nb <= 256)
__global__ void scan2_k(int* __restrict__ bsum, int nb) {
    __shared__ int sh[256];
    int tid = threadIdx.x;
    int v = (tid < nb) ? bsum[tid] : 0;
    sh[tid] = v;
    __syncthreads();
    for (int off = 1; off < 256; off <<= 1) {
        int t = (tid >= off) ? sh[tid - off] : 0;
        __syncthreads();
        sh[tid] += t;
        __syncthreads();
    }
    if (tid < nb) bsum[tid] = sh[tid] - v;
}

__global__ void scan3_k(int* __restrict__ row, const int* __restrict__ bsum) {
    int i = blockIdx.x * blockDim.x + threadIdx.x;
    if (i < N_NODES) row[i] += bsum[i >> 10];
    if (i == 0) row[N_NODES] = NNZ;
}

// reorder edges by destination: sorted[pos] = (src, val)
__global__ void place_k(const int* __restrict__ src, const int* __restrict__ dst,
                        const float* __restrict__ val, const int* __restrict__ row,
                        int* __restrict__ off, int2* __restrict__ sorted) {
    int e = blockIdx.x * blockDim.x + threadIdx.x;
    if (e >= NNZ) return;
    int d = dst[e];
    int pos = row[d] + atomicAdd(&off[d], 1);
    sorted[pos] = make_int2(src[e], __float_as_int(val[e]));
}

// ---------------- gather SpMM: Y[d] = sum val*X[src]; ACC += Y ---------------
__global__ void gather_k(const int* __restrict__ row, const int2* __restrict__ se,
                         const float* __restrict__ X, float* __restrict__ Y,
                         float* __restrict__ ACC) {
    int wid  = (blockIdx.x * blockDim.x + threadIdx.x) >> 6;   // node
    int lane = threadIdx.x & 63;                               // dim
    if (wid >= N_NODES) return;
    int beg = row[wid], end = row[wid + 1];
    float acc = 0.f;
    for (int base = beg; base < end; base += 64) {
        int rem = end - base;
        int2 ev = make_int2(0, 0);
        if (lane < rem) ev = se[base + lane];
        int n = rem < 64 ? rem : 64;
        for (int j = 0; j < n; ++j) {
            int   s = __shfl(ev.x, j, 64);
            float v = __int_as_float(__shfl(ev.y, j, 64));
            acc += v * X[(size_t)s * 64 + lane];
        }
    }
    size_t o = (size_t)wid * 64 + lane;
    Y[o]   = acc;
    ACC[o] += acc;
}

// ---------------- final: gather rows, dot, sigmoid ---------------------------
__global__ void final_k(const int* __restrict__ users, const int* __restrict__ items,
                        const float* __restrict__ ACC, float* __restrict__ out) {
    int b    = blockIdx.x * (blockDim.x / 64) + (threadIdx.x / 64);
    int lane = threadIdx.x & 63;
    if (b >= BATCH) return;
    int ur = users[b];
    int ir = N_USERS + items[b];
    float u  = ACC[ur * 64 + lane];
    float it = ACC[ir * 64 + lane];
    float p  = u * it * (1.0f / 16.0f);   // light_out = acc/4 on both sides
    #pragma unroll
    for (int off = 32; off; off >>= 1) p += __shfl_down(p, off, 64);
    if (lane == 0) out[b] = 1.0f / (1.0f + __expf(-p));
}

extern "C" void kernel_launch(void* const* d_in, const int* in_sizes, int n_in,
                              void* d_out, int out_size, void* d_ws, size_t ws_size,
                              hipStream_t stream) {
    const int*   users = (const int*)  d_in[0];
    const int*   items = (const int*)  d_in[1];
    const int*   esrc  = (const int*)  d_in[2];
    const int*   edst  = (const int*)  d_in[3];
    const float* eval  = (const float*)d_in[4];
    const float* uemb  = (const float*)d_in[5];
    const float* iemb  = (const float*)d_in[6];
    float*       out   = (float*)      d_out;

    const size_t EMB = (size_t)N_NODES * DIM * sizeof(float);      // 38.4 MB
    char* ws = (char*)d_ws;
    float* X      = (float*)(ws);
    float* Y      = (float*)(ws + EMB);
    float* ACC    = (float*)(ws + 2 * EMB);
    int2*  sorted = (int2*) (ws + 3 * EMB);                        // 32 MB
    char*  ws2    = ws + 3 * EMB + (size_t)NNZ * sizeof(int2);
    int*   row    = (int*)(ws2);                                   // N_NODES+1
    int*   cnt    = (int*)(ws2 + ((N_NODES + 2) * 4 + 255) / 256 * 256);
    int*   bsum   = (int*)((char*)cnt + ((N_NODES)     * 4 + 255) / 256 * 256);

    const int totv = N_NODES * DIM / 4;
    init_k<<<(totv + 255) / 256, 256, 0, stream>>>(
        (const float4*)uemb, (const float4*)iemb, (float4*)X, (float4*)ACC);

    // ---- CSR build (by destination) ----
    hipMemsetAsync(cnt, 0, (size_t)N_NODES * 4, stream);
    hist_k<<<(NNZ + 255) / 256, 256, 0, stream>>>(edst, cnt);
    const int NB = (N_NODES + 1023) / 1024;                        // 147
    scan1_k<<<NB, 256, 0, stream>>>(cnt, row, bsum);
    scan2_k<<<1, 256, 0, stream>>>(bsum, NB);
    scan3_k<<<(N_NODES + 255) / 256, 256, 0, stream>>>(row, bsum);
    hipMemsetAsync(cnt, 0, (size_t)N_NODES * 4, stream);           // reuse as off
    place_k<<<(NNZ + 255) / 256, 256, 0, stream>>>(esrc, edst, eval, row, cnt, sorted);

    // ---- 3 gather layers, ACC fused ----
    const int gthreads = N_NODES * 64;
    for (int l = 0; l < 3; ++l) {
        gather_k<<<(gthreads + 255) / 256, 256, 0, stream>>>(row, sorted, X, Y, ACC);
        float* tmp = X; X = Y; Y = tmp;
    }

    final_k<<<(BATCH * 64 + 255) / 256, 256, 0, stream>>>(users, items, ACC, out);
}